// Round 10
// baseline (139.583 us; speedup 1.0000x reference)
//
#include <hip/hip_runtime.h>

#define HH 128
#define WW 128
#define BB 4
#define CC 64
#define CHN 21
#define NPIX (HH*WW)     // 16384
#define NTAP 24
#define PAD 4
#define PW 136
#define PH 136
#define PPLANE (PW*PH)   // 18496
#define PWQ (PW/4)       // 34
#define AGR 4            // affinity channel groups per block
#define ACH (CC/AGR)     // 16 channels per thread
#define CG 7             // channels per prop thread
#define NCG (CHN/CG)     // 3

typedef _Float16 h4 __attribute__((ext_vector_type(4)));
typedef _Float16 h8 __attribute__((ext_vector_type(8)));

// Compile-time tap offsets in the padded plane (row stride PW, element units).
constexpr int TAPOFF[NTAP] = {
    -PW-1, -PW, -PW+1, -1, 1, PW-1, PW, PW+1,
    -2*PW-2, -2*PW, -2*PW+2, -2, 2, 2*PW-2, 2*PW, 2*PW+2,
    -4*PW-4, -4*PW, -4*PW+4, -4, 4, 4*PW-4, 4*PW, 4*PW+4
};

__device__ __forceinline__ int clampi(int v, int lo, int hi) {
    return v < lo ? lo : (v > hi ? hi : v);
}

// ---- pad: edge-replicate feats AND mask into padded fp16 planes ------------
__global__ __launch_bounds__(256) void pad_kernel(
    const float* __restrict__ feats, const float* __restrict__ mask,
    _Float16* __restrict__ pfeats, _Float16* __restrict__ pmask) {
    int t = blockIdx.x * blockDim.x + threadIdx.x;
    const int nfp = BB * CC;
    const int total = (nfp + BB * CHN) * PH * PWQ;
    if (t >= total) return;
    int q = t % PWQ;
    int rest = t / PWQ;
    int ph = rest % PH;
    int pl = rest / PH;
    const float* src;
    _Float16* dst;
    if (pl < nfp) { src = feats + (size_t)pl * NPIX; dst = pfeats + (size_t)pl * PPLANE; }
    else { src = mask + (size_t)(pl - nfp) * NPIX; dst = pmask + (size_t)(pl - nfp) * PPLANE; }
    const float* sp = src + (size_t)clampi(ph - PAD, 0, HH - 1) * WW;
    h4 v;
    v[0] = (_Float16)sp[clampi(q * 4 + 0 - PAD, 0, WW - 1)];
    v[1] = (_Float16)sp[clampi(q * 4 + 1 - PAD, 0, WW - 1)];
    v[2] = (_Float16)sp[clampi(q * 4 + 2 - PAD, 0, WW - 1)];
    v[3] = (_Float16)sp[clampi(q * 4 + 3 - PAD, 0, WW - 1)];
    *((h4*)(dst + (size_t)ph * PW + q * 4)) = v;
}

// ---- fused affinity: block = 64 px x 4 channel-groups; LDS reduce ----------
// aff output: h8 quads, layout [b][3][NPIX] (each quad = 8 taps, fp16).
__global__ __launch_bounds__(256) void affinity_kernel(
    const _Float16* __restrict__ pfeats, h8* __restrict__ aff) {
    __shared__ float red[AGR][64][NTAP + 1];   // stride 25: conflict-free

    int t = threadIdx.x;
    int g = t >> 6;                  // 0..3 channel group
    int px = t & 63;                 // 0..63 pixel in half-row
    int blk = blockIdx.x;            // 0..1023
    int w = (blk & 1) * 64 + px;
    int h = (blk >> 1) & 127;
    int b = blk >> 8;

    const _Float16* base0 = pfeats + (size_t)(b * CC + g * ACH) * PPLANE
                          + (size_t)(h + PAD) * PW + (w + PAD);

    float acc[NTAP];
    #pragma unroll
    for (int k = 0; k < NTAP; ++k) acc[k] = 0.f;

    for (int c = 0; c < ACH; ++c) {
        const _Float16* base = base0 + (size_t)c * PPLANE;
        float q = (float)base[0];
        float sum = 3.f * q, ss = 3.f * q * q;   // center window x3 dilations
        float v[NTAP];
        #pragma unroll
        for (int k = 0; k < NTAP; ++k) {
            float x = (float)base[TAPOFF[k]];
            v[k] = x;
            sum += x;
            ss = fmaf(x, x, ss);
        }
        float var = (ss - sum * sum * (1.f/27.f)) * (1.f/26.f);
        float inv = 1.f / (1e-8f + 0.1f * sqrtf(fmaxf(var, 0.f)));
        #pragma unroll
        for (int k = 0; k < NTAP; ++k)
            acc[k] = fmaf(fabsf(v[k] - q), inv, acc[k]);   // positive sum; negate later
    }

    #pragma unroll
    for (int k = 0; k < NTAP; ++k) red[g][px][k] = acc[k];
    __syncthreads();

    if (t < 64) {
        float s[NTAP];
        #pragma unroll
        for (int k = 0; k < NTAP; ++k)
            s[k] = (red[0][t][k] + red[1][t][k]) + (red[2][t][k] + red[3][t][k]);
        float mn = s[0];
        #pragma unroll
        for (int k = 1; k < NTAP; ++k) mn = fminf(mn, s[k]);
        float e[NTAP];
        float tot = 0.f;
        #pragma unroll
        for (int k = 0; k < NTAP; ++k) {
            e[k] = __expf((mn - s[k]) * (1.f/CC));
            tot += e[k];
        }
        float ivt = 1.f / tot;
        int pix = h * WW + (blk & 1) * 64 + t;
        #pragma unroll
        for (int j = 0; j < 3; ++j) {
            h8 q;
            #pragma unroll
            for (int i = 0; i < 8; ++i) q[i] = (_Float16)(e[8*j + i] * ivt);
            aff[((size_t)b * 3 + j) * NPIX + pix] = q;
        }
    }
}

// ---- prop: 1 px x 7 ch per thread; fp16 planes; f32 accumulate -------------
__global__ __launch_bounds__(256, 3) void prop_kernel(
    const _Float16* __restrict__ psrc_all, const h8* __restrict__ aff,
    _Float16* __restrict__ dstp, float* __restrict__ dstf, int final_iter) {
    int idx = blockIdx.x * 256 + threadIdx.x;   // global px 0..65535
    int cg = blockIdx.y;                        // 0..2
    int w = idx & 127;
    int h = (idx >> 7) & 127;
    int b = idx >> 14;
    int pix = idx & (NPIX - 1);

    float A[NTAP];
    #pragma unroll
    for (int j = 0; j < 3; ++j) {
        h8 q = aff[((size_t)b * 3 + j) * NPIX + pix];
        #pragma unroll
        for (int i = 0; i < 8; ++i) A[8*j + i] = (float)q[i];
    }

    #pragma unroll
    for (int cc = 0; cc < CG; ++cc) {
        int ch = cg * CG + cc;
        const _Float16* base = psrc_all + (size_t)(b * CHN + ch) * PPLANE
                             + (size_t)(h + PAD) * PW + (w + PAD);
        float r = 0.f;
        #pragma unroll
        for (int k = 0; k < NTAP; ++k) r = fmaf(A[k], (float)base[TAPOFF[k]], r);

        if (final_iter) {
            dstf[(size_t)(b * CHN + ch) * NPIX + pix] = r;
        } else {
            _Float16* pd = dstp + (size_t)(b * CHN + ch) * PPLANE;
            _Float16 rh = (_Float16)r;
            int pr = (h + PAD) * PW;
            pd[pr + PAD + w] = rh;
            h4 e; e[0] = rh; e[1] = rh; e[2] = rh; e[3] = rh;
            if (w == 0)      *((h4*)(pd + pr)) = e;
            if (w == WW-1)   *((h4*)(pd + pr + PAD + WW)) = e;
            if (h == 0) {
                #pragma unroll
                for (int rr = 0; rr < PAD; ++rr) {
                    pd[rr * PW + PAD + w] = rh;
                    if (w == 0)    *((h4*)(pd + rr * PW)) = e;
                    if (w == WW-1) *((h4*)(pd + rr * PW + PAD + WW)) = e;
                }
            }
            if (h == HH-1) {
                #pragma unroll
                for (int rr = 0; rr < PAD; ++rr) {
                    int r2 = (PH - 1 - rr) * PW;
                    pd[r2 + PAD + w] = rh;
                    if (w == 0)    *((h4*)(pd + r2)) = e;
                    if (w == WW-1) *((h4*)(pd + r2 + PAD + WW)) = e;
                }
            }
        }
    }
}

extern "C" void kernel_launch(void* const* d_in, const int* in_sizes, int n_in,
                              void* d_out, int out_size, void* d_ws, size_t ws_size,
                              hipStream_t stream) {
    const float* feats = (const float*)d_in[0];
    const float* mask  = (const float*)d_in[1];
    float* out = (float*)d_out;

    const size_t pfeatsE = (size_t)BB * CC * PPLANE;    // halfs
    const size_t pbufE   = (size_t)BB * CHN * PPLANE;   // halfs
    const size_t affQ    = (size_t)BB * 3 * NPIX;       // h8 elems (16B each)

    _Float16* pfeats = (_Float16*)d_ws;
    _Float16* pbuf0  = pfeats + pfeatsE;
    _Float16* pbuf1  = pbuf0 + pbufE;
    h8*       aff    = (h8*)(pbuf1 + pbufE);            // 16B aligned (offsets even)

    {
        int total = (BB * CC + BB * CHN) * PH * PWQ;
        pad_kernel<<<dim3((total + 255) / 256), dim3(256), 0, stream>>>(feats, mask, pfeats, pbuf0);
    }
    affinity_kernel<<<dim3(BB * NPIX / 64), dim3(256), 0, stream>>>(pfeats, aff);

    const _Float16* src = pbuf0;
    for (int it = 1; it <= 10; ++it) {
        if (it < 10) {
            _Float16* dst = (it & 1) ? pbuf1 : pbuf0;
            prop_kernel<<<dim3(256, NCG), dim3(256), 0, stream>>>(src, aff, dst, nullptr, 0);
            src = dst;
        } else {
            prop_kernel<<<dim3(256, NCG), dim3(256), 0, stream>>>(src, aff, nullptr, out, 1);
        }
    }
}

// Round 11
// 130.457 us; speedup vs baseline: 1.0700x; 1.0700x over previous
//
#include <hip/hip_runtime.h>

#define HH 128
#define WW 128
#define BB 4
#define CC 64
#define CHN 21
#define CHP 24           // padded channel count (channel-last layout, 48 B/px)
#define NPIX (HH*WW)     // 16384
#define NTAP 24
#define PAD 4
#define PW 136
#define PH 136
#define PPLANE (PW*PH)   // 18496
#define PWQ (PW/4)       // 34
#define AGR 4            // affinity channel groups per block
#define ACH (CC/AGR)     // 16 channels per thread

typedef _Float16 h4 __attribute__((ext_vector_type(4)));
typedef _Float16 h8 __attribute__((ext_vector_type(8)));

// Compile-time tap offsets in the padded plane (row stride PW, pixel units).
constexpr int TAPOFF[NTAP] = {
    -PW-1, -PW, -PW+1, -1, 1, PW-1, PW, PW+1,
    -2*PW-2, -2*PW, -2*PW+2, -2, 2, 2*PW-2, 2*PW, 2*PW+2,
    -4*PW-4, -4*PW, -4*PW+4, -4, 4, 4*PW-4, 4*PW, 4*PW+4
};

__device__ __forceinline__ int clampi(int v, int lo, int hi) {
    return v < lo ? lo : (v > hi ? hi : v);
}

// ---- pad feats: edge-replicate [B,C,128,128] f32 -> [B,C,136,136] fp16 -----
__global__ __launch_bounds__(256) void pad_feats_kernel(
    const float* __restrict__ feats, _Float16* __restrict__ pfeats) {
    int t = blockIdx.x * blockDim.x + threadIdx.x;
    const int total = BB * CC * PH * PWQ;
    if (t >= total) return;
    int q = t % PWQ;
    int rest = t / PWQ;
    int ph = rest % PH;
    int pl = rest / PH;
    const float* sp = feats + (size_t)pl * NPIX + (size_t)clampi(ph - PAD, 0, HH - 1) * WW;
    h4 v;
    v[0] = (_Float16)sp[clampi(q * 4 + 0 - PAD, 0, WW - 1)];
    v[1] = (_Float16)sp[clampi(q * 4 + 1 - PAD, 0, WW - 1)];
    v[2] = (_Float16)sp[clampi(q * 4 + 2 - PAD, 0, WW - 1)];
    v[3] = (_Float16)sp[clampi(q * 4 + 3 - PAD, 0, WW - 1)];
    *((h4*)(pfeats + (size_t)pl * PPLANE + (size_t)ph * PW + q * 4)) = v;
}

// ---- pad+transpose mask: [B,21,128,128] f32 -> [B,136*136,24] fp16 ---------
__global__ __launch_bounds__(256) void pad_mask_kernel(
    const float* __restrict__ mask, _Float16* __restrict__ pm) {
    int t = blockIdx.x * blockDim.x + threadIdx.x;
    const int total = BB * PPLANE;
    if (t >= total) return;
    int pp = t % PPLANE;
    int b = t / PPLANE;
    int ph = pp / PW, pw = pp % PW;
    int sh = clampi(ph - PAD, 0, HH - 1);
    int sw = clampi(pw - PAD, 0, WW - 1);
    const float* sp = mask + (size_t)b * CHN * NPIX + (size_t)sh * WW + sw;
    _Float16* dp = pm + ((size_t)b * PPLANE + pp) * CHP;
    h8 o0, o1, o2;
    #pragma unroll
    for (int c = 0; c < 8; ++c)  o0[c] = (_Float16)sp[(size_t)c * NPIX];
    #pragma unroll
    for (int c = 0; c < 8; ++c)  o1[c] = (_Float16)sp[(size_t)(c + 8) * NPIX];
    #pragma unroll
    for (int c = 0; c < 5; ++c)  o2[c] = (_Float16)sp[(size_t)(c + 16) * NPIX];
    o2[5] = (_Float16)0.f; o2[6] = (_Float16)0.f; o2[7] = (_Float16)0.f;
    *((h8*)(dp + 0))  = o0;
    *((h8*)(dp + 8))  = o1;
    *((h8*)(dp + 16)) = o2;
}

// ---- fused affinity (unchanged from R9): fp16 feats, h8 aff out ------------
// aff layout: [b][3][NPIX] h8 quads (8 taps each, fp16).
__global__ __launch_bounds__(256) void affinity_kernel(
    const _Float16* __restrict__ pfeats, h8* __restrict__ aff) {
    __shared__ float red[AGR][64][NTAP + 1];

    int t = threadIdx.x;
    int g = t >> 6;
    int px = t & 63;
    int blk = blockIdx.x;
    int w = (blk & 1) * 64 + px;
    int h = (blk >> 1) & 127;
    int b = blk >> 8;

    const _Float16* base0 = pfeats + (size_t)(b * CC + g * ACH) * PPLANE
                          + (size_t)(h + PAD) * PW + (w + PAD);

    float acc[NTAP];
    #pragma unroll
    for (int k = 0; k < NTAP; ++k) acc[k] = 0.f;

    for (int c = 0; c < ACH; ++c) {
        const _Float16* base = base0 + (size_t)c * PPLANE;
        float q = (float)base[0];
        float sum = 3.f * q, ss = 3.f * q * q;
        float v[NTAP];
        #pragma unroll
        for (int k = 0; k < NTAP; ++k) {
            float x = (float)base[TAPOFF[k]];
            v[k] = x;
            sum += x;
            ss = fmaf(x, x, ss);
        }
        float var = (ss - sum * sum * (1.f/27.f)) * (1.f/26.f);
        float inv = 1.f / (1e-8f + 0.1f * sqrtf(fmaxf(var, 0.f)));
        #pragma unroll
        for (int k = 0; k < NTAP; ++k)
            acc[k] = fmaf(fabsf(v[k] - q), inv, acc[k]);
    }

    #pragma unroll
    for (int k = 0; k < NTAP; ++k) red[g][px][k] = acc[k];
    __syncthreads();

    if (t < 64) {
        float s[NTAP];
        #pragma unroll
        for (int k = 0; k < NTAP; ++k)
            s[k] = (red[0][t][k] + red[1][t][k]) + (red[2][t][k] + red[3][t][k]);
        float mn = s[0];
        #pragma unroll
        for (int k = 1; k < NTAP; ++k) mn = fminf(mn, s[k]);
        float e[NTAP];
        float tot = 0.f;
        #pragma unroll
        for (int k = 0; k < NTAP; ++k) {
            e[k] = __expf((mn - s[k]) * (1.f/CC));
            tot += e[k];
        }
        float ivt = 1.f / tot;
        int pix = h * WW + (blk & 1) * 64 + t;
        #pragma unroll
        for (int j = 0; j < 3; ++j) {
            h8 q;
            #pragma unroll
            for (int i = 0; i < 8; ++i) q[i] = (_Float16)(e[8*j + i] * ivt);
            aff[((size_t)b * 3 + j) * NPIX + pix] = q;
        }
    }
}

// ---- prop: channel-last packed. thread = (px, 8-ch group) ------------------
// src/dst: [b][PPLANE][24] fp16. aff: [b][3][NPIX] h8. f32 accumulate.
__global__ __launch_bounds__(256) void prop_kernel(
    const _Float16* __restrict__ src, const h8* __restrict__ aff,
    _Float16* __restrict__ dstp, float* __restrict__ dstf, int final_iter) {
    int idx = blockIdx.x * 256 + threadIdx.x;   // global px 0..65535
    int cg = blockIdx.y;                        // 0..2 (channels cg*8..cg*8+7)
    int w = idx & 127;
    int h = (idx >> 7) & 127;
    int b = idx >> 14;
    int pix = idx & (NPIX - 1);

    // all 24 tap weights
    float A[NTAP];
    #pragma unroll
    for (int j = 0; j < 3; ++j) {
        h8 q = aff[((size_t)b * 3 + j) * NPIX + pix];
        #pragma unroll
        for (int i = 0; i < 8; ++i) A[8*j + i] = (float)q[i];
    }

    const int pp = (h + PAD) * PW + (w + PAD);
    const _Float16* base = src + ((size_t)b * PPLANE + pp) * CHP + cg * 8;

    float acc[8];
    #pragma unroll
    for (int i = 0; i < 8; ++i) acc[i] = 0.f;

    #pragma unroll
    for (int k = 0; k < NTAP; ++k) {
        h8 m = *((const h8*)(base + (ptrdiff_t)TAPOFF[k] * CHP));
        #pragma unroll
        for (int i = 0; i < 8; ++i)
            acc[i] = fmaf((float)m[i], A[k], acc[i]);
    }

    if (final_iter) {
        float* ob = dstf + (size_t)b * CHN * NPIX + pix;
        #pragma unroll
        for (int i = 0; i < 8; ++i) {
            int ch = cg * 8 + i;
            if (ch < CHN) ob[(size_t)ch * NPIX] = acc[i];
        }
    } else {
        h8 o;
        #pragma unroll
        for (int i = 0; i < 8; ++i) o[i] = (_Float16)acc[i];
        _Float16* pd = dstp + (size_t)b * PPLANE * CHP + cg * 8;
        // interior store + edge/corner halo replication
        int x0 = (w == 0) ? -PAD : 0, x1 = (w == WW-1) ? PAD : 0;
        int y0 = (h == 0) ? -PAD : 0, y1 = (h == HH-1) ? PAD : 0;
        for (int dy = y0; dy <= y1; ++dy)
            for (int dx = x0; dx <= x1; ++dx)
                *((h8*)(pd + (size_t)(pp + dy * PW + dx) * CHP)) = o;
    }
}

extern "C" void kernel_launch(void* const* d_in, const int* in_sizes, int n_in,
                              void* d_out, int out_size, void* d_ws, size_t ws_size,
                              hipStream_t stream) {
    const float* feats = (const float*)d_in[0];
    const float* mask  = (const float*)d_in[1];
    float* out = (float*)d_out;

    const size_t pfeatsE = (size_t)BB * CC * PPLANE;        // halfs
    const size_t affQ    = (size_t)BB * 3 * NPIX;           // h8 (16 B each)
    const size_t pmE     = (size_t)BB * PPLANE * CHP;       // halfs

    _Float16* pfeats = (_Float16*)d_ws;
    h8*       aff    = (h8*)(pfeats + pfeatsE);
    _Float16* pm0    = (_Float16*)((char*)aff + affQ * sizeof(h8));
    _Float16* pm1    = pm0 + pmE;

    {
        int total = BB * CC * PH * PWQ;
        pad_feats_kernel<<<dim3((total + 255) / 256), dim3(256), 0, stream>>>(feats, pfeats);
    }
    {
        int total = BB * PPLANE;
        pad_mask_kernel<<<dim3((total + 255) / 256), dim3(256), 0, stream>>>(mask, pm0);
    }
    affinity_kernel<<<dim3(BB * NPIX / 64), dim3(256), 0, stream>>>(pfeats, aff);

    const _Float16* src = pm0;
    for (int it = 1; it <= 10; ++it) {
        if (it < 10) {
            _Float16* dst = (it & 1) ? pm1 : pm0;
            prop_kernel<<<dim3(256, 3), dim3(256), 0, stream>>>(src, aff, dst, nullptr, 0);
            src = dst;
        } else {
            prop_kernel<<<dim3(256, 3), dim3(256), 0, stream>>>(src, aff, nullptr, out, 1);
        }
    }
}